// Round 2
// baseline (144.723 us; speedup 1.0000x reference)
//
#include <hip/hip_runtime.h>

// Fused Bahdanau context-attention pooling, MI355X (gfx950).
//   K1 prep    : q = query@Wq^T (f32), Wk -> bf16 copy in ws, mask-layout flag
//   K2 main    : ONE WAVE per (b, 32-row s-chunk), barrier-free:
//                A-frags global f32 -> reg bf16, B-frags from bf16 Wk (L2-hot),
//                full 128-col projection in one wave's accs, score = sum_a
//                tanh(q+k)*Ws via in-wave shuffles, chunk (m,d) + partial ctx.
//   K3 combine : per b: global M, D; context; weights.

typedef __attribute__((ext_vector_type(8))) short short8;
typedef __attribute__((ext_vector_type(4))) float f32x4;

#define S_LEN 4096
#define BATCH 32
#define KVD 512
#define AD 128
#define SCHN 32
#define CHUNKS_PER_B (S_LEN / SCHN)    // 128
#define NCHUNK (BATCH * CHUNKS_PER_B)  // 4096

// ws byte offsets
#define FLAG_OFF   0
#define Q_OFF      1024
#define WK_OFF     17408
#define SCORES_OFF 148480
#define MD_OFF     672768
#define CTXP_OFF   705536

__device__ __forceinline__ unsigned short f2bf(float f) {
  unsigned int u = __float_as_uint(f);
  u = (u + 0x7FFFu + ((u >> 16) & 1u)) >> 16;  // round-to-nearest-even
  return (unsigned short)u;
}
__device__ __forceinline__ float tanh_fast(float x) {
  // exp overflow -> inf -> 1.0; underflow -> 0 -> -1.0 : correct saturation
  return 1.0f - 2.0f / (1.0f + __expf(2.0f * x));
}
__device__ __forceinline__ short8 pack8(float4 lo, float4 hi) {
  short8 r;
  r[0] = (short)f2bf(lo.x); r[1] = (short)f2bf(lo.y);
  r[2] = (short)f2bf(lo.z); r[3] = (short)f2bf(lo.w);
  r[4] = (short)f2bf(hi.x); r[5] = (short)f2bf(hi.y);
  r[6] = (short)f2bf(hi.z); r[7] = (short)f2bf(hi.w);
  return r;
}

__global__ __launch_bounds__(256) void prep_kernel(
    const float* __restrict__ query, const float* __restrict__ Wq,
    const float* __restrict__ Wk, const void* __restrict__ maskp,
    float* __restrict__ qws, unsigned short* __restrict__ wkb,
    int* __restrict__ flagp) {
  int blk = blockIdx.x, t = threadIdx.x;
  if (blk < 32) {
    // q[blk][a] = sum_k query[blk][k] * Wq[a][k]
    __shared__ float qrow[KVD];
    qrow[t] = query[blk * KVD + t];
    qrow[t + 256] = query[blk * KVD + t + 256];
    __syncthreads();
    int a = t >> 1, half = t & 1;
    const float4* wq4 = (const float4*)(Wq + (size_t)a * KVD + half * 256);
    const float4* qr4 = (const float4*)(qrow + half * 256);
    float s = 0.f;
#pragma unroll 8
    for (int i = 0; i < 64; ++i) {
      float4 wv = wq4[i], qv = qr4[i];
      s += wv.x * qv.x + wv.y * qv.y + wv.z * qv.z + wv.w * qv.w;
    }
    s += __shfl_xor(s, 1);
    if (half == 0) qws[blk * AD + a] = s;
  } else if (blk < 40) {
    // Wk f32 -> bf16 (AD*KVD = 65536 elems = 16384 float4s, 8 blocks)
    int j = blk - 32;
    const float4* src = (const float4*)Wk;
#pragma unroll 4
    for (int i = 0; i < 8; ++i) {
      int idx4 = j * 2048 + i * 256 + t;
      float4 v = src[idx4];
      ushort4 o;
      o.x = f2bf(v.x); o.y = f2bf(v.y); o.z = f2bf(v.z); o.w = f2bf(v.w);
      ((ushort4*)wkb)[idx4] = o;
    }
  } else {
    // mask layout detection: int32 0/1 words vs packed bool bytes
    __shared__ int okv;
    if (t == 0) okv = 1;
    __syncthreads();
    if (t < 128) {
      int wv = ((const int*)maskp)[t];
      if (!(wv == 0 || wv == 1)) okv = 0;  // benign race, all write 0
    }
    __syncthreads();
    if (t == 0) flagp[0] = okv;  // 1 = int32 layout, 0 = byte layout
  }
}

__global__ __launch_bounds__(256, 3) void main_kernel(
    const float* __restrict__ kv, const void* __restrict__ maskp,
    const float* __restrict__ Ws, const float* __restrict__ qws,
    const unsigned short* __restrict__ wkb, const int* __restrict__ flagp,
    float* __restrict__ scores, float* __restrict__ md,
    float* __restrict__ ctxp) {
  int t = threadIdx.x;
  int lane = t & 63, wave = t >> 6;
  int g = blockIdx.x * 4 + wave;       // global 32-row tile id, b-major
  int b = g >> 7, chunk = g & 127;
  int s0 = chunk * SCHN;
  int lr = lane & 15, lg = lane >> 4;

  __shared__ float esc[4][SCHN];
  __shared__ float ssc[4][SCHN];

  // A rows: s = s0 + 16*mi + lr ; k-offset lg*8 within each 32-wide k-step
  const float* arow0 = kv + ((size_t)b * S_LEN + s0 + lr) * KVD + lg * 8;
  const float* arow1 = arow0 + (size_t)16 * KVD;
  // B rows: a = 16*n + lr
  const unsigned short* brow = wkb + (size_t)lr * KVD + lg * 8;

  f32x4 acc[2][8];
#pragma unroll
  for (int mi = 0; mi < 2; ++mi)
#pragma unroll
    for (int n = 0; n < 8; ++n) acc[mi][n] = (f32x4)0.f;

  for (int kk = 0; kk < KVD / 32; ++kk) {
    int ko = kk * 32;
    // A from HBM first (long latency), then B from L2
    float4 a0lo = *(const float4*)(arow0 + ko);
    float4 a0hi = *(const float4*)(arow0 + ko + 4);
    float4 a1lo = *(const float4*)(arow1 + ko);
    float4 a1hi = *(const float4*)(arow1 + ko + 4);
    short8 bfr[8];
#pragma unroll
    for (int n = 0; n < 8; ++n)
      bfr[n] = *(const short8*)(brow + (size_t)n * 16 * KVD + ko);
    short8 af0 = pack8(a0lo, a0hi);
    short8 af1 = pack8(a1lo, a1hi);
#pragma unroll
    for (int n = 0; n < 8; ++n) {
      acc[0][n] = __builtin_amdgcn_mfma_f32_16x16x32_bf16(af0, bfr[n], acc[0][n], 0, 0, 0);
      acc[1][n] = __builtin_amdgcn_mfma_f32_16x16x32_bf16(af1, bfr[n], acc[1][n], 0, 0, 0);
    }
  }

  // ---- scores: sum_a tanh(q[a] + k[s][a]) * Ws[a] ----
  // D layout: col a = 16n + lr, row s = s0 + 16mi + 4lg + reg
  float qv[8], wv[8];
#pragma unroll
  for (int n = 0; n < 8; ++n) {
    qv[n] = qws[b * AD + n * 16 + lr];
    wv[n] = Ws[n * 16 + lr];
  }
  int flag = flagp[0];
  float sc[2][4];
#pragma unroll
  for (int mi = 0; mi < 2; ++mi) {
#pragma unroll
    for (int reg = 0; reg < 4; ++reg) {
      float v = 0.f;
#pragma unroll
      for (int n = 0; n < 8; ++n)
        v += tanh_fast(qv[n] + acc[mi][n][reg]) * wv[n];
      v += __shfl_xor(v, 1);
      v += __shfl_xor(v, 2);
      v += __shfl_xor(v, 4);
      v += __shfl_xor(v, 8);   // all lanes now hold row-sum for (lg,mi,reg)
      int gs = b * S_LEN + s0 + 16 * mi + 4 * lg + reg;
      int mk = flag ? ((const int*)maskp)[gs]
                    : (int)((const unsigned char*)maskp)[gs];
      sc[mi][reg] = mk ? v : -INFINITY;
    }
  }

  // ---- in-wave online softmax over the 32 rows ----
  float m = -INFINITY;
#pragma unroll
  for (int mi = 0; mi < 2; ++mi)
#pragma unroll
    for (int reg = 0; reg < 4; ++reg) m = fmaxf(m, sc[mi][reg]);
  m = fmaxf(m, __shfl_xor(m, 16));
  m = fmaxf(m, __shfl_xor(m, 32));
  float e[2][4];
  float d = 0.f;
#pragma unroll
  for (int mi = 0; mi < 2; ++mi)
#pragma unroll
    for (int reg = 0; reg < 4; ++reg) {
      e[mi][reg] = (sc[mi][reg] == -INFINITY) ? 0.f : __expf(sc[mi][reg] - m);
      d += e[mi][reg];
    }
  d += __shfl_xor(d, 16);
  d += __shfl_xor(d, 32);

  if (lr == 0) {
#pragma unroll
    for (int mi = 0; mi < 2; ++mi)
#pragma unroll
      for (int reg = 0; reg < 4; ++reg) {
        int srow = 16 * mi + 4 * lg + reg;
        esc[wave][srow] = e[mi][reg];
        ssc[wave][srow] = sc[mi][reg];
      }
  }
  if (lane == 0) { md[g * 2] = m; md[g * 2 + 1] = d; }
  __syncthreads();  // publish esc/ssc (only barrier in the kernel)

  if (lane < SCHN) scores[b * S_LEN + s0 + lane] = ssc[wave][lane];

  // ---- partial context: ctx[c] = sum_s e_s * kv[s][c], c = lane*8..+7 ----
  float4 c0 = make_float4(0.f, 0.f, 0.f, 0.f);
  float4 c1 = make_float4(0.f, 0.f, 0.f, 0.f);
  const float* kvc = kv + ((size_t)b * S_LEN + s0) * KVD + lane * 8;
#pragma unroll 4
  for (int s = 0; s < SCHN; ++s) {
    float ev = esc[wave][s];
    float4 v0 = *(const float4*)(kvc + (size_t)s * KVD);
    float4 v1 = *(const float4*)(kvc + (size_t)s * KVD + 4);
    c0.x += ev * v0.x; c0.y += ev * v0.y; c0.z += ev * v0.z; c0.w += ev * v0.w;
    c1.x += ev * v1.x; c1.y += ev * v1.y; c1.z += ev * v1.z; c1.w += ev * v1.w;
  }
  float* cp = ctxp + (size_t)g * KVD + lane * 8;
  *(float4*)cp = c0;
  *(float4*)(cp + 4) = c1;
}

__global__ __launch_bounds__(512) void combine_kernel(
    const float* __restrict__ md, const float* __restrict__ ctxp,
    const float* __restrict__ scores, float* __restrict__ out) {
  int b = blockIdx.x, t = threadIdx.x;
  __shared__ float mv[CHUNKS_PER_B], dv[CHUNKS_PER_B], scl[CHUNKS_PER_B];
  __shared__ float Msh, Dsh;
  if (t < CHUNKS_PER_B) {
    mv[t] = md[(b * CHUNKS_PER_B + t) * 2];
    dv[t] = md[(b * CHUNKS_PER_B + t) * 2 + 1];
  }
  __syncthreads();
  if (t < 64) {
    float m = fmaxf(mv[t], mv[t + 64]);
    m = fmaxf(m, __shfl_xor(m, 32));
    m = fmaxf(m, __shfl_xor(m, 16));
    m = fmaxf(m, __shfl_xor(m, 8));
    m = fmaxf(m, __shfl_xor(m, 4));
    m = fmaxf(m, __shfl_xor(m, 2));
    m = fmaxf(m, __shfl_xor(m, 1));
    if (t == 0) Msh = m;
  }
  __syncthreads();
  float M = Msh;
  if (t < CHUNKS_PER_B) scl[t] = (dv[t] > 0.f) ? __expf(mv[t] - M) : 0.f;
  __syncthreads();
  if (t < 64) {
    float d = scl[t] * dv[t] + scl[t + 64] * dv[t + 64];
    d += __shfl_xor(d, 32);
    d += __shfl_xor(d, 16);
    d += __shfl_xor(d, 8);
    d += __shfl_xor(d, 4);
    d += __shfl_xor(d, 2);
    d += __shfl_xor(d, 1);
    if (t == 0) Dsh = d;
  }
  __syncthreads();
  float invD = 1.f / Dsh;
  // context
  for (int c = t; c < KVD; c += 512) {
    float sum = 0.f;
#pragma unroll 4
    for (int j = 0; j < CHUNKS_PER_B; ++j)
      sum += scl[j] * ctxp[(size_t)(b * CHUNKS_PER_B + j) * KVD + c];
    out[b * KVD + c] = sum * invD;
  }
  // weights
  for (int s = t; s < S_LEN; s += 512) {
    float sc = scores[b * S_LEN + s];
    out[BATCH * KVD + b * S_LEN + s] = __expf(sc - M) * invD;  // -inf -> 0
  }
}

extern "C" void kernel_launch(void* const* d_in, const int* in_sizes, int n_in,
                              void* d_out, int out_size, void* d_ws, size_t ws_size,
                              hipStream_t stream) {
  const float* query = (const float*)d_in[0];
  const float* kv    = (const float*)d_in[1];
  const void*  maskp = d_in[2];
  const float* Wq    = (const float*)d_in[3];
  const float* Wk    = (const float*)d_in[4];
  const float* Ws    = (const float*)d_in[5];
  float* out = (float*)d_out;
  char* w = (char*)d_ws;
  int* flagp = (int*)(w + FLAG_OFF);
  float* qws = (float*)(w + Q_OFF);
  unsigned short* wkb = (unsigned short*)(w + WK_OFF);
  float* scores = (float*)(w + SCORES_OFF);
  float* md = (float*)(w + MD_OFF);
  float* ctxp = (float*)(w + CTXP_OFF);

  prep_kernel<<<41, 256, 0, stream>>>(query, Wq, Wk, maskp, qws, wkb, flagp);
  main_kernel<<<NCHUNK / 4, 256, 0, stream>>>(kv, maskp, Ws, qws, wkb, flagp,
                                              scores, md, ctxp);
  combine_kernel<<<BATCH, 512, 0, stream>>>(md, ctxp, scores, out);
}

// Round 3
// 134.860 us; speedup vs baseline: 1.0731x; 1.0731x over previous
//
#include <hip/hip_runtime.h>

// Fused Bahdanau context-attention pooling, MI355X (gfx950).
//   K1 prep     : q = query@Wq^T (f32), Wk -> bf16 in ws, mask-layout flag
//   K2 main     : ONE WAVE per (b, 32-row s-chunk), zero cross-wave coupling:
//                 kv chunk HBM -> XOR-swizzled bf16 LDS tile (single HBM pass),
//                 k = kv@Wk^T via mfma_f32_16x16x32_bf16 (full 128 a-cols in
//                 one wave's accs), score = sum_a tanh(q+k)*Ws, in-wave chunk
//                 softmax (m,d), partial context from the LDS tile.
//   K3 combineA : per b: global M, D from 128 chunk (m,d); scl[j]=e^(m_j-M)/D
//   K4 combineB : context = sum_j scl_j*ctxp_j ; weights = exp(score-M)/D
//
// LDS tile swizzle: byte ^= ((row&7)<<4) on 16B blocks. Conflict-free for
// stage writes (8B pairs move together), MFMA A ds_read_b128 (slot =
// (kk*4+lg)^(lr&7) distinct within each 8-lane group), and context reads.

typedef __attribute__((ext_vector_type(8))) short short8;
typedef __attribute__((ext_vector_type(4))) float f32x4;

#define S_LEN 4096
#define BATCH 32
#define KVD 512
#define AD 128
#define SCHN 32
#define CHUNKS_PER_B (S_LEN / SCHN)    // 128
#define NCHUNK (BATCH * CHUNKS_PER_B)  // 4096

// ws byte offsets
#define FLAG_OFF   0
#define Q_OFF      1024
#define WK_OFF     17408       // + 128*512*2 = 131072
#define SCORES_OFF 148480      // + 32*4096*4 = 524288
#define MD_OFF     672768      // + 4096*2*4  = 32768
#define CTXP_OFF   705536      // + 4096*512*4 = 8388608
#define SCL_OFF    9094144     // + 32*128*4  = 16384
#define MD2_OFF    9110528     // + 32*2*4

__device__ __forceinline__ unsigned short f2bf_rne(float f) {
  unsigned int u = __float_as_uint(f);
  u = (u + 0x7FFFu + ((u >> 16) & 1u)) >> 16;
  return (unsigned short)u;
}
// cheap round-half-up pack of 2 f32 -> 1 dword of 2 bf16 (lo, hi)
__device__ __forceinline__ unsigned int packbf(float a, float b) {
  unsigned int lo = __float_as_uint(a) + 0x8000u;
  unsigned int hi = __float_as_uint(b) + 0x8000u;
  return (lo >> 16) | (hi & 0xFFFF0000u);
}
__device__ __forceinline__ float tanh_fast(float x) {
  return 1.0f - 2.0f / (1.0f + __expf(2.0f * x));
}

__global__ __launch_bounds__(256) void prep_kernel(
    const float* __restrict__ query, const float* __restrict__ Wq,
    const float* __restrict__ Wk, const void* __restrict__ maskp,
    float* __restrict__ qws, unsigned short* __restrict__ wkb,
    int* __restrict__ flagp) {
  int blk = blockIdx.x, t = threadIdx.x;
  if (blk < 32) {
    __shared__ float qrow[KVD];
    qrow[t] = query[blk * KVD + t];
    qrow[t + 256] = query[blk * KVD + t + 256];
    __syncthreads();
    int a = t >> 1, half = t & 1;
    const float4* wq4 = (const float4*)(Wq + (size_t)a * KVD + half * 256);
    const float4* qr4 = (const float4*)(qrow + half * 256);
    float s = 0.f;
#pragma unroll 8
    for (int i = 0; i < 64; ++i) {
      float4 wv = wq4[i], qv = qr4[i];
      s += wv.x * qv.x + wv.y * qv.y + wv.z * qv.z + wv.w * qv.w;
    }
    s += __shfl_xor(s, 1);
    if (half == 0) qws[blk * AD + a] = s;
  } else if (blk < 40) {
    int j = blk - 32;
    const float4* src = (const float4*)Wk;
#pragma unroll 4
    for (int i = 0; i < 8; ++i) {
      int idx4 = j * 2048 + i * 256 + t;
      float4 v = src[idx4];
      ushort4 o;
      o.x = f2bf_rne(v.x); o.y = f2bf_rne(v.y);
      o.z = f2bf_rne(v.z); o.w = f2bf_rne(v.w);
      ((ushort4*)wkb)[idx4] = o;
    }
  } else {
    __shared__ int okv;
    if (t == 0) okv = 1;
    __syncthreads();
    if (t < 128) {
      int wv = ((const int*)maskp)[t];
      if (!(wv == 0 || wv == 1)) okv = 0;
    }
    __syncthreads();
    if (t == 0) flagp[0] = okv;  // 1 = int32 layout, 0 = byte layout
  }
}

__global__ __launch_bounds__(64) void main_kernel(
    const float* __restrict__ kv, const void* __restrict__ maskp,
    const float* __restrict__ Ws, const float* __restrict__ qws,
    const unsigned short* __restrict__ wkb, const int* __restrict__ flagp,
    float* __restrict__ scores, float* __restrict__ md,
    float* __restrict__ ctxp) {
  int lane = threadIdx.x;
  int g = blockIdx.x;
  int b = g >> 7, chunk = g & (CHUNKS_PER_B - 1);
  int s0 = chunk * SCHN;
  int lr = lane & 15, lg = lane >> 4;

  __shared__ char tileb[SCHN * 1024];  // 32 rows x 512 bf16, XOR-swizzled
  __shared__ float escf[SCHN];

  // early independent loads (L2), overlap with staging
  int flag = flagp[0];
  int mload = 0;
  if (lane < SCHN) {
    int gs = b * S_LEN + s0 + lane;
    mload = flag ? ((const int*)maskp)[gs]
                 : (int)((const unsigned char*)maskp)[gs];
  }
  float qv[8], wv[8];
#pragma unroll
  for (int n = 0; n < 8; ++n) {
    qv[n] = qws[b * AD + n * 16 + lr];
    wv[n] = Ws[n * 16 + lr];
  }

  // ---- stage kv chunk (32x512 f32, contiguous 64KB) -> swizzled bf16 LDS ----
  const float* src = kv + ((size_t)b * S_LEN + s0) * KVD;
#pragma unroll 8
  for (int r = 0; r < SCHN; ++r) {
    float4 v0 = *(const float4*)(src + (size_t)r * KVD + lane * 4);
    float4 v1 = *(const float4*)(src + (size_t)r * KVD + 256 + lane * 4);
    uint2 w0, w1;
    w0.x = packbf(v0.x, v0.y); w0.y = packbf(v0.z, v0.w);
    w1.x = packbf(v1.x, v1.y); w1.y = packbf(v1.z, v1.w);
    int xr = (r & 7) << 4;
    *(uint2*)(tileb + ((r * 1024 + lane * 8) ^ xr)) = w0;
    *(uint2*)(tileb + ((r * 1024 + 512 + lane * 8) ^ xr)) = w1;
  }
  __syncthreads();  // single wave: compiler fence + lgkmcnt drain

  // ---- projection: C[s(32)][a(128)] = kv @ Wk^T, 16x16x32 bf16 MFMA ----
  f32x4 acc[2][8];
#pragma unroll
  for (int mi = 0; mi < 2; ++mi)
#pragma unroll
    for (int n = 0; n < 8; ++n) acc[mi][n] = (f32x4)0.f;

  const unsigned short* brow = wkb + (size_t)lr * KVD + lg * 8;
  const char* ta0 = tileb + lr * 1024;
  const char* ta1 = tileb + (16 + lr) * 1024;  // (16+lr)&7 == lr&7
  int axor = (lr & 7) << 4;

  for (int kk = 0; kk < KVD / 32; ++kk) {
    int ko = (kk * 64 + lg * 16) ^ axor;
    short8 af0 = *(const short8*)(ta0 + ko);
    short8 af1 = *(const short8*)(ta1 + ko);
#pragma unroll
    for (int n = 0; n < 8; ++n) {
      short8 bf = *(const short8*)(brow + (size_t)n * 16 * KVD + kk * 32);
      acc[0][n] = __builtin_amdgcn_mfma_f32_16x16x32_bf16(af0, bf, acc[0][n], 0, 0, 0);
      acc[1][n] = __builtin_amdgcn_mfma_f32_16x16x32_bf16(af1, bf, acc[1][n], 0, 0, 0);
    }
  }

  // ---- scores: sum_a tanh(q[a] + k[s][a]) * Ws[a] ----
  // D layout: col a = 16n + lr, row s = 16mi + 4lg + reg
  float sc[2][4];
#pragma unroll
  for (int mi = 0; mi < 2; ++mi) {
#pragma unroll
    for (int reg = 0; reg < 4; ++reg) {
      float v = 0.f;
#pragma unroll
      for (int n = 0; n < 8; ++n)
        v += tanh_fast(qv[n] + acc[mi][n][reg]) * wv[n];
      v += __shfl_xor(v, 1);
      v += __shfl_xor(v, 2);
      v += __shfl_xor(v, 4);
      v += __shfl_xor(v, 8);
      int row = 16 * mi + 4 * lg + reg;
      int mk = __shfl(mload, row);
      sc[mi][reg] = mk ? v : -INFINITY;
    }
  }

  // ---- in-wave softmax over the 32 rows ----
  float m = -INFINITY;
#pragma unroll
  for (int mi = 0; mi < 2; ++mi)
#pragma unroll
    for (int reg = 0; reg < 4; ++reg) m = fmaxf(m, sc[mi][reg]);
  m = fmaxf(m, __shfl_xor(m, 16));
  m = fmaxf(m, __shfl_xor(m, 32));
  float e[2][4];
  float d = 0.f;
#pragma unroll
  for (int mi = 0; mi < 2; ++mi)
#pragma unroll
    for (int reg = 0; reg < 4; ++reg) {
      e[mi][reg] = (sc[mi][reg] == -INFINITY) ? 0.f : __expf(sc[mi][reg] - m);
      d += e[mi][reg];
    }
  d += __shfl_xor(d, 16);
  d += __shfl_xor(d, 32);

  if (lr == 0) {
#pragma unroll
    for (int mi = 0; mi < 2; ++mi)
#pragma unroll
      for (int reg = 0; reg < 4; ++reg) {
        int row = 16 * mi + 4 * lg + reg;
        escf[row] = e[mi][reg];
        scores[b * S_LEN + s0 + row] = sc[mi][reg];
      }
  }
  if (lane == 0) { md[g * 2] = m; md[g * 2 + 1] = d; }
  __syncthreads();  // single wave: escf/tileb fence

  // ---- partial context from LDS tile: ctx[c] = sum_s e_s * kv[s][c] ----
  float4 c0 = make_float4(0.f, 0.f, 0.f, 0.f);
  float4 c1 = make_float4(0.f, 0.f, 0.f, 0.f);
#pragma unroll 4
  for (int s = 0; s < SCHN; ++s) {
    float ev = escf[s];
    uint4 u = *(const uint4*)(tileb + ((s * 1024 + lane * 16) ^ ((s & 7) << 4)));
    c0.x += ev * __uint_as_float(u.x << 16);
    c0.y += ev * __uint_as_float(u.x & 0xFFFF0000u);
    c0.z += ev * __uint_as_float(u.y << 16);
    c0.w += ev * __uint_as_float(u.y & 0xFFFF0000u);
    c1.x += ev * __uint_as_float(u.z << 16);
    c1.y += ev * __uint_as_float(u.z & 0xFFFF0000u);
    c1.z += ev * __uint_as_float(u.w << 16);
    c1.w += ev * __uint_as_float(u.w & 0xFFFF0000u);
  }
  float* cp = ctxp + (size_t)g * KVD + lane * 8;
  *(float4*)cp = c0;
  *(float4*)(cp + 4) = c1;
}

__global__ __launch_bounds__(128) void combineA_kernel(
    const float* __restrict__ md, float* __restrict__ scl,
    float* __restrict__ md2) {
  int b = blockIdx.x, t = threadIdx.x;  // 128 threads = 2 waves
  float mv = md[(b * CHUNKS_PER_B + t) * 2];
  float dv = md[(b * CHUNKS_PER_B + t) * 2 + 1];
  __shared__ float rmax[2], rsum[2];
  float m = mv;
  m = fmaxf(m, __shfl_xor(m, 1));
  m = fmaxf(m, __shfl_xor(m, 2));
  m = fmaxf(m, __shfl_xor(m, 4));
  m = fmaxf(m, __shfl_xor(m, 8));
  m = fmaxf(m, __shfl_xor(m, 16));
  m = fmaxf(m, __shfl_xor(m, 32));
  if ((t & 63) == 0) rmax[t >> 6] = m;
  __syncthreads();
  float M = fmaxf(rmax[0], rmax[1]);
  float e = (dv > 0.f) ? __expf(mv - M) : 0.f;
  float pd = e * dv;
  pd += __shfl_xor(pd, 1);
  pd += __shfl_xor(pd, 2);
  pd += __shfl_xor(pd, 4);
  pd += __shfl_xor(pd, 8);
  pd += __shfl_xor(pd, 16);
  pd += __shfl_xor(pd, 32);
  if ((t & 63) == 0) rsum[t >> 6] = pd;
  __syncthreads();
  float D = rsum[0] + rsum[1];
  float invD = 1.f / D;
  scl[b * CHUNKS_PER_B + t] = e * invD;
  if (t == 0) { md2[b * 2] = M; md2[b * 2 + 1] = invD; }
}

__global__ __launch_bounds__(256) void combineB_kernel(
    const float* __restrict__ scl, const float* __restrict__ md2,
    const float* __restrict__ ctxp, const float* __restrict__ scores,
    float* __restrict__ out) {
  int strip = blockIdx.x, b = blockIdx.y, t = threadIdx.x;
  if (strip < 8) {
    // context: 64 cols per strip, 4-way j-split
    __shared__ float part[4][64];
    int c = strip * 64 + (t & 63);
    int jg = t >> 6;
    float sum = 0.f;
    for (int j = jg; j < CHUNKS_PER_B; j += 4)
      sum += scl[b * CHUNKS_PER_B + j] *
             ctxp[(size_t)(b * CHUNKS_PER_B + j) * KVD + c];
    part[jg][t & 63] = sum;
    __syncthreads();
    if (t < 64)
      out[b * KVD + c] = part[0][t] + part[1][t] + part[2][t] + part[3][t];
  } else {
    // weights: 1024 s per strip
    float M = md2[b * 2], invD = md2[b * 2 + 1];
    int sbase = (strip - 8) * 1024;
#pragma unroll
    for (int i = 0; i < 4; ++i) {
      int s = sbase + i * 256 + t;
      float scv = scores[b * S_LEN + s];
      out[BATCH * KVD + b * S_LEN + s] = __expf(scv - M) * invD;  // -inf -> 0
    }
  }
}

extern "C" void kernel_launch(void* const* d_in, const int* in_sizes, int n_in,
                              void* d_out, int out_size, void* d_ws, size_t ws_size,
                              hipStream_t stream) {
  const float* query = (const float*)d_in[0];
  const float* kv    = (const float*)d_in[1];
  const void*  maskp = d_in[2];
  const float* Wq    = (const float*)d_in[3];
  const float* Wk    = (const float*)d_in[4];
  const float* Ws    = (const float*)d_in[5];
  float* out = (float*)d_out;
  char* w = (char*)d_ws;
  int* flagp = (int*)(w + FLAG_OFF);
  float* qws = (float*)(w + Q_OFF);
  unsigned short* wkb = (unsigned short*)(w + WK_OFF);
  float* scores = (float*)(w + SCORES_OFF);
  float* md = (float*)(w + MD_OFF);
  float* ctxp = (float*)(w + CTXP_OFF);
  float* scl = (float*)(w + SCL_OFF);
  float* md2 = (float*)(w + MD2_OFF);

  prep_kernel<<<41, 256, 0, stream>>>(query, Wq, Wk, maskp, qws, wkb, flagp);
  main_kernel<<<NCHUNK, 64, 0, stream>>>(kv, maskp, Ws, qws, wkb, flagp,
                                         scores, md, ctxp);
  combineA_kernel<<<BATCH, 128, 0, stream>>>(md, scl, md2);
  combineB_kernel<<<dim3(12, BATCH), 256, 0, stream>>>(scl, md2, ctxp, scores, out);
}